// Round 20
// baseline (131.381 us; speedup 1.0000x reference)
//
#include <hip/hip_runtime.h>
#include <hip/hip_bf16.h>
#include <math.h>

#define DIM 1024
#define NB  4096      // B
#define N2  8192      // 2B
#define BT  256       // full tile dim
#define NT2 32        // N2 / BT
#define PS  34        // partials stride: 32 col-tile slots + aux + pad
#define GRID_FULL 512 // 528 tiles - 16 quartered diagonals
#define GRID_ALL  576 // + 64 quarter jobs

#define C1f 8.9447146e-4f    // 10*log2(e)/127^2
#define C2f 3.5778876e-4f    // 4*log2(e)/127^2
#define C2b (-5.7707802f)    // -4*log2(e)

typedef int i32x4 __attribute__((ext_vector_type(4)));

__device__ __forceinline__ void gload_lds16(const unsigned char* g, unsigned char* l) {
    __builtin_amdgcn_global_load_lds((__attribute__((address_space(1))) void*)(g),
                                     (__attribute__((address_space(3))) void*)(l),
                                     16, 0, 0);
}

// pack 4 int8 (round-to-nearest of x*127; |x|<=1 so no clamp needed)
__device__ __forceinline__ unsigned int pk4_i8(float a, float b, float c, float d) {
    const int ia = __float2int_rn(a * 127.0f), ib = __float2int_rn(b * 127.0f);
    const int ic = __float2int_rn(c * 127.0f), id = __float2int_rn(d * 127.0f);
    return (unsigned)(ia & 255) | ((unsigned)(ib & 255) << 8) |
           ((unsigned)(ic & 255) << 16) | ((unsigned)(id & 255) << 24);
}

// ---------------- Kernel 1: normalize rows, emit i8 z (k-interleaved), pos --
// Column permutation within each 64-block (row-independent): a bijection on
// instruction-k applied to BOTH MFMA operands => cancels in the dot product.
__global__ __launch_bounds__(256) void norm_kernel(
    const float* __restrict__ p1, const float* __restrict__ p2,
    unsigned char* __restrict__ zq, float* __restrict__ pos)
{
    const int r = blockIdx.x;
    const int t = threadIdx.x;
    const float4 x1 = ((const float4*)(p1 + (size_t)r * DIM))[t];
    const float4 x2 = ((const float4*)(p2 + (size_t)r * DIM))[t];
    float s1  = x1.x*x1.x + x1.y*x1.y + x1.z*x1.z + x1.w*x1.w;
    float s2  = x2.x*x2.x + x2.y*x2.y + x2.z*x2.z + x2.w*x2.w;
    float s12 = x1.x*x2.x + x1.y*x2.y + x1.z*x2.z + x1.w*x2.w;
#pragma unroll
    for (int off = 1; off < 64; off <<= 1) {
        s1  += __shfl_xor(s1,  off);
        s2  += __shfl_xor(s2,  off);
        s12 += __shfl_xor(s12, off);
    }
    __shared__ float ls[3][4];
    const int wid = t >> 6;
    if ((t & 63) == 0) { ls[0][wid] = s1; ls[1][wid] = s2; ls[2][wid] = s12; }
    __syncthreads();
    s1  = ls[0][0] + ls[0][1] + ls[0][2] + ls[0][3];
    s2  = ls[1][0] + ls[1][1] + ls[1][2] + ls[1][3];
    s12 = ls[2][0] + ls[2][1] + ls[2][2] + ls[2][3];
    const float rn1 = 1.0f / fmaxf(sqrtf(s1), 1e-12f);
    const float rn2 = 1.0f / fmaxf(sqrtf(s2), 1e-12f);
    if (t == 0) pos[r] = s12 * rn1 * rn2;

    const int j0 = (t << 2) & 63;       // col within 64-block
    const int kb = t >> 4;              // 64-block index
    const int pb = (j0 < 32) ? (((j0 >> 3) << 4) + (j0 & 7))
                             : ((((j0 - 32) >> 3) << 4) + 8 + ((j0 - 32) & 7));
    const size_t off8 = (size_t)kb * 64 + pb;
    *(unsigned int*)(zq + (size_t)r * DIM + off8) =
        pk4_i8(x1.x * rn1, x1.y * rn1, x1.z * rn1, x1.w * rn1);
    *(unsigned int*)(zq + (size_t)(NB + r) * DIM + off8) =
        pk4_i8(x2.x * rn2, x2.y * rn2, x2.z * rn2, x2.w * rn2);
}

// ------- Kernel 2: i8 symmetric z.z^T; 512 full 256^2 tiles + 64 quarters ---
// A staged in LDS (swizzled, conflict-free); B operands read DIRECT from
// global: a B-frag is 16 rows x 64 consecutive bytes = 16 full cache lines,
// perfectly coalesced, per-phase B working set 16 KB (L1-resident), shared by
// the 4 waves of each wc column -> L1 hits on the otherwise-idle TA pipe.
// Halves LDS-pipe reads (2048->1024 b128/job) and deletes B staging.
// A k-interleave swizzle un-XORs to logical granule kg; B loads granule kg
// natively -> identical k-order on both operands, dot product exact.
__global__ __launch_bounds__(1024, 4) void sim_kernel(
    const unsigned char* __restrict__ zq,
    float* __restrict__ partials,    // [N2][PS], zeroed before launch
    float* __restrict__ lup)         // [NT2*NT2], full-tile rt<=ct slots
{
    __shared__ __align__(16) unsigned char buf[2][BT * 128]; // A only, 64 KB
    const int t    = threadIdx.x;
    const int lane = t & 63;
    const int wid  = t >> 6;       // 0..15
    const int fr   = lane & 15;    // fragment row (A) / col (B)
    const int kg   = lane >> 4;    // k-group 0..3
    const int cb0  = ((kg ^ (fr & 7)) << 4);                 // h=0 swizzled slot
    const int sgr8 = (((lane & 7) ^ ((lane >> 3) & 7)) << 4); // involution src
    const int rsub = (lane >> 4) << 2;
    const int csub = lane & 15;
    const int bid = blockIdx.x;

    if (bid < GRID_FULL) {
        // ---------------- full 256x256 tile ----------------
        int jj = (bid & 7) * 64 + (bid >> 3);   // bijective XCD swizzle
#pragma unroll 1
        for (int k = 16; k < 32; ++k) {         // skip quartered diag tiles
            const int e = k * 32 - ((k * (k - 1)) >> 1);
            if (jj >= e) ++jj;
        }
        int rt = 0;
        while ((rt + 1) * 32 - (((rt + 1) * rt) >> 1) <= jj) ++rt;
        const int ct = rt + jj - (rt * 32 - ((rt * (rt - 1)) >> 1));
        const bool isdiag = (rt == ct);
        const int row0 = rt << 8;
        const int col0 = ct << 8;
        const int wr = wid >> 2;    // 0..3 (64-row strip)
        const int wc = wid & 3;     // 0..3 (64-col strip)

        const int abase = ((wr << 6) + fr) << 7;   // LDS row stride 128

        // A staging: 32 chunks of 8 rows x 128B, 2 per wave; lane l: row l>>3,
        // LDS slot l&7 (linear), pre-swizzled global granule sgr8
        const unsigned char* asrc =
            zq + (size_t)(row0 + (wid << 4) + (lane >> 3)) * DIM + sgr8;
        // B direct-global per-lane base: row = col0 + wc*64 + fr, byte kg*16
        const unsigned char* bptr =
            zq + (size_t)(col0 + (wc << 6) + fr) * DIM + (kg << 4);

#define STAGEA(bsel, kp) do { \
        gload_lds16(asrc + (kp) * 128,                   &buf[bsel][(wid << 11)]); \
        gload_lds16(asrc + (size_t)8 * DIM + (kp) * 128, &buf[bsel][(wid << 11) + 1024]); \
    } while (0)

        i32x4 acc[4][4] = {};
        STAGEA(0, 0);
        __syncthreads();

#pragma unroll
        for (int kp = 0; kp < 8; ++kp) {
            const int cur = kp & 1;
            if (kp < 7) STAGEA(cur ^ 1, kp + 1);
            const unsigned char* Ab = &buf[cur][0] + abase;
            const unsigned char* bk = bptr + kp * 128;
#pragma unroll
            for (int h = 0; h < 2; ++h) {
                const int cbh = cb0 ^ (h << 6);
                i32x4 bq[4];
#pragma unroll
                for (int n = 0; n < 4; ++n)
                    bq[n] = *(const i32x4*)(bk + (size_t)(n << 4) * DIM + (h << 6));
#pragma unroll
                for (int m = 0; m < 4; ++m) {
                    const i32x4 aq = *(const i32x4*)(Ab + (m << 11) + cbh);
#pragma unroll
                    for (int n = 0; n < 4; ++n)
                        acc[m][n] = __builtin_amdgcn_mfma_i32_16x16x64_i8(aq, bq[n], acc[m][n], 0, 0, 0);
                }
            }
            __syncthreads();
        }
#undef STAGEA

        // ---- epilogue: C/D layout col=lane&15, row=(lane>>4)*4+reg ----
        float* rsum4 = (float*)&buf[0][0];      // [256][4] per-(row,wc)
        float* csum4 = rsum4 + 1024;            // [256][4] per-(col,wr)
        float* lured = csum4 + 1024;            // [16]
        const bool inreg = (ct < 8) || (rt >= 8 && ct < 16);  // lunif blocks
        const int  rbase = row0 + (wr << 6);
        const int  cbase = col0 + (wc << 6);

        float lu = 0.0f;
        float cs[4] = {0.0f, 0.0f, 0.0f, 0.0f};
#pragma unroll
        for (int m = 0; m < 4; ++m) {
            float rs[4] = {0.0f, 0.0f, 0.0f, 0.0f};
#pragma unroll
            for (int n = 0; n < 4; ++n) {
                const int gcol = cbase + (n << 4) + csub;
#pragma unroll
                for (int r = 0; r < 4; ++r) {
                    const int grow = rbase + (m << 4) + rsub + r;
                    const float f = (float)acc[m][n][r];
                    float e = exp2f(f * C1f);
                    if (isdiag) e = (grow != gcol) ? e : 0.0f;
                    rs[r] += e;
                    cs[n] += e;
                    if (inreg && (!isdiag || gcol > grow))
                        lu += exp2f(fmaf(f, C2f, C2b));
                }
            }
#pragma unroll
            for (int off = 1; off < 16; off <<= 1) {
#pragma unroll
                for (int r = 0; r < 4; ++r) rs[r] += __shfl_xor(rs[r], off);
            }
            if ((lane & 15) == 0) {
#pragma unroll
                for (int r = 0; r < 4; ++r)
                    rsum4[((wr << 6) + (m << 4) + rsub + r) * 4 + wc] = rs[r];
            }
        }
        if (!isdiag) {
#pragma unroll
            for (int off = 16; off < 64; off <<= 1) {
#pragma unroll
                for (int n = 0; n < 4; ++n) cs[n] += __shfl_xor(cs[n], off);
            }
            if (lane < 16) {
#pragma unroll
                for (int n = 0; n < 4; ++n)
                    csum4[((wc << 6) + (n << 4) + lane) * 4 + wr] = cs[n];
            }
        }
#pragma unroll
        for (int off = 1; off < 64; off <<= 1) lu += __shfl_xor(lu, off);
        if (lane == 0) lured[wid] = lu;
        __syncthreads();

        if (t == 0) {
            float s = 0.0f;
#pragma unroll
            for (int w = 0; w < 16; ++w) s += lured[w];
            lup[rt * NT2 + ct] = s;
        }
        if (t < 256) {
            const float* p = rsum4 + t * 4;
            partials[(size_t)(row0 + t) * PS + ct] = ((p[0] + p[1]) + p[2]) + p[3];
        } else if (t < 512 && !isdiag) {
            const float* p = csum4 + (t - 256) * 4;
            partials[(size_t)(col0 + t - 256) * PS + rt] = ((p[0] + p[1]) + p[2]) + p[3];
        }
    } else {
        // ------------- quarter 128x128 of diag tile (k,k), k=16..31 --------
        const int q  = bid - GRID_FULL;
        const int k  = 16 + (q >> 2);
        const int qr = (q >> 1) & 1;
        const int qc = q & 1;
        const int row0 = (k << 8) + (qr << 7);
        const int col0 = (k << 8) + (qc << 7);
        const int wr = wid >> 2;    // 0..3 (32-row strip)
        const int wc = wid & 3;     // 0..3 (32-col strip)

        // A staging: 16 chunks of 8 rows, 1 per wave
        const unsigned char* asrc =
            zq + (size_t)(row0 + (wid << 3) + (lane >> 3)) * DIM + sgr8;
        const unsigned char* bptr =
            zq + (size_t)(col0 + (wc << 5) + fr) * DIM + (kg << 4);

        i32x4 acc[2][2] = {};
        gload_lds16(asrc, &buf[0][wid << 10]);
        __syncthreads();

#pragma unroll
        for (int kp = 0; kp < 8; ++kp) {
            const int cur = kp & 1;
            if (kp < 7) gload_lds16(asrc + (kp + 1) * 128, &buf[cur ^ 1][wid << 10]);
            const unsigned char* Ab = &buf[cur][0] + (((wr << 5) + fr) << 7);
            const unsigned char* bk = bptr + kp * 128;
#pragma unroll
            for (int h = 0; h < 2; ++h) {
                const int cbh = cb0 ^ (h << 6);
                i32x4 aq[2], bq[2];
#pragma unroll
                for (int n = 0; n < 2; ++n)
                    bq[n] = *(const i32x4*)(bk + (size_t)(n << 4) * DIM + (h << 6));
#pragma unroll
                for (int m = 0; m < 2; ++m)
                    aq[m] = *(const i32x4*)(Ab + (m << 11) + cbh);
#pragma unroll
                for (int m = 0; m < 2; ++m)
#pragma unroll
                    for (int n = 0; n < 2; ++n)
                        acc[m][n] = __builtin_amdgcn_mfma_i32_16x16x64_i8(aq[m], bq[n], acc[m][n], 0, 0, 0);
            }
            __syncthreads();
        }

        // epilogue: rowsum only (z_j diag region: no colsum, no lunif)
        float* rsum4 = (float*)&buf[0][0];      // [128][4] per-(row,wc)
#pragma unroll
        for (int m = 0; m < 2; ++m) {
            float rs[4] = {0.0f, 0.0f, 0.0f, 0.0f};
#pragma unroll
            for (int n = 0; n < 2; ++n) {
                const int gcol = col0 + (wc << 5) + (n << 4) + csub;
#pragma unroll
                for (int r = 0; r < 4; ++r) {
                    const int grow = row0 + (wr << 5) + (m << 4) + rsub + r;
                    float e = exp2f((float)acc[m][n][r] * C1f);
                    e = (grow != gcol) ? e : 0.0f;   // diag mask (qr==qc quads)
                    rs[r] += e;
                }
            }
#pragma unroll
            for (int off = 1; off < 16; off <<= 1) {
#pragma unroll
                for (int r = 0; r < 4; ++r) rs[r] += __shfl_xor(rs[r], off);
            }
            if ((lane & 15) == 0) {
#pragma unroll
                for (int r = 0; r < 4; ++r)
                    rsum4[((wr << 5) + (m << 4) + rsub + r) * 4 + wc] = rs[r];
            }
        }
        __syncthreads();
        if (t < 128) {
            const float* p = rsum4 + t * 4;
            partials[(size_t)(row0 + t) * PS + (qc ? 32 : k)] =
                ((p[0] + p[1]) + p[2]) + p[3];
        }
    }
}

// --------- Kernel 3a: per-row denom -> log, 128 rows per block --------------
__global__ __launch_bounds__(128) void logred_kernel(
    const float* __restrict__ partials, double* __restrict__ red_log)
{
    const int t   = threadIdx.x;
    const int row = blockIdx.x * 128 + t;
    const float* p = partials + (size_t)row * PS;
    float dsum = 0.0f;
#pragma unroll
    for (int i = 0; i < 33; ++i) dsum += p[i];   // 32 main + aux slot 32
    double l = log((double)dsum);
    __shared__ double sd[128];
    sd[t] = l;
    __syncthreads();
    for (int s = 64; s > 0; s >>= 1) {
        if (t < s) sd[t] += sd[t + s];
        __syncthreads();
    }
    if (t == 0) red_log[blockIdx.x] = sd[0];
}

// --------- Kernel 3b: final scalars --------------------------------------
__global__ __launch_bounds__(256) void final_kernel(
    const double* __restrict__ red_log, const float* __restrict__ pos,
    const float* __restrict__ lup, float* __restrict__ out)
{
    const int t = threadIdx.x;
    double dlog = 0.0, dpos = 0.0, ds1 = 0.0, ds2 = 0.0;
    if (t < 64) dlog = red_log[t];
    for (int i = t; i < NB; i += 256) dpos += (double)pos[i];
    for (int i = t; i < NT2 * NT2; i += 256) {
        const int rt = i >> 5, ct = i & 31;
        if (rt > ct) continue;                 // only upper-tri tiles written
        const double v = (double)lup[i];
        if (rt < 8 && ct < 8) ds1 += v;
        else if (rt >= 8 && rt < 16 && ct >= 8 && ct < 16) ds2 += v;
    }
    __shared__ double sd[4][256];
    sd[0][t] = dlog; sd[1][t] = dpos; sd[2][t] = ds1; sd[3][t] = ds2;
    __syncthreads();
    for (int s = 128; s > 0; s >>= 1) {
        if (t < s) {
            sd[0][t] += sd[0][t + s]; sd[1][t] += sd[1][t + s];
            sd[2][t] += sd[2][t + s]; sd[3][t] += sd[3][t + s];
        }
        __syncthreads();
    }
    if (t == 0) {
        const double mean_pos = sd[1][0] / (double)NB;
        const double loss   = sd[0][0] / (double)N2 - mean_pos * 10.0;   // /TEMP
        const double lalign = 2.0 - 2.0 * mean_pos;
        const double C      = 2048.0 * 2047.0 * 0.5;
        const double lunif  = 0.5 * (log(sd[2][0] / C) + log(sd[3][0] / C));
        out[0] = (float)loss;
        out[1] = (float)lalign;
        out[2] = (float)lunif;
    }
}

extern "C" void kernel_launch(void* const* d_in, const int* in_sizes, int n_in,
                              void* d_out, int out_size, void* d_ws, size_t ws_size,
                              hipStream_t stream) {
    const float* p1 = (const float*)d_in[0];
    const float* p2 = (const float*)d_in[1];
    float* out = (float*)d_out;

    char* ws = (char*)d_ws;
    unsigned char* zq = (unsigned char*)ws;                              // 8 MB
    float*  partials  = (float*)(ws + ((size_t)8 << 20));                // ~1.1 MB [8192][34]
    float*  pos       = (float*)(ws + ((size_t)10 << 20));               // 16 KB
    float*  lup       = (float*)(ws + ((size_t)10 << 20) + 16384);       // 4 KB
    double* red_log   = (double*)(ws + ((size_t)10 << 20) + 16384 + 4096); // 512 B

    hipMemsetAsync(partials, 0, (size_t)N2 * PS * sizeof(float), stream);
    hipLaunchKernelGGL(norm_kernel,   dim3(NB),       dim3(256),  0, stream, p1, p2, zq, pos);
    hipLaunchKernelGGL(sim_kernel,    dim3(GRID_ALL), dim3(1024), 0, stream, zq, partials, lup);
    hipLaunchKernelGGL(logred_kernel, dim3(64),       dim3(128),  0, stream, partials, red_log);
    hipLaunchKernelGGL(final_kernel,  dim3(1),        dim3(256),  0, stream, red_log, pos, lup, out);
}

// Round 21
// 75.489 us; speedup vs baseline: 1.7404x; 1.7404x over previous
//
#include <hip/hip_runtime.h>
#include <hip/hip_bf16.h>
#include <math.h>

#define DIM 1024
#define NB  4096      // B
#define N2  8192      // 2B
#define BT  256       // full tile dim
#define NT2 32        // N2 / BT
#define PS  34        // partials stride: 32 col-tile slots + aux + pad
#define GRID_FULL 512 // 528 tiles - 16 quartered diagonals
#define GRID_ALL  576 // + 64 quarter jobs

#define C1f 8.9447146e-4f    // 10*log2(e)/127^2
#define C2f 3.5778876e-4f    // 4*log2(e)/127^2
#define C2b (-5.7707802f)    // -4*log2(e)

typedef int i32x4 __attribute__((ext_vector_type(4)));

__device__ __forceinline__ void gload_lds16(const unsigned char* g, unsigned char* l) {
    __builtin_amdgcn_global_load_lds((__attribute__((address_space(1))) void*)(g),
                                     (__attribute__((address_space(3))) void*)(l),
                                     16, 0, 0);
}

// pack 4 int8 (round-to-nearest of x*127; |x|<=1 so no clamp needed)
__device__ __forceinline__ unsigned int pk4_i8(float a, float b, float c, float d) {
    const int ia = __float2int_rn(a * 127.0f), ib = __float2int_rn(b * 127.0f);
    const int ic = __float2int_rn(c * 127.0f), id = __float2int_rn(d * 127.0f);
    return (unsigned)(ia & 255) | ((unsigned)(ib & 255) << 8) |
           ((unsigned)(ic & 255) << 16) | ((unsigned)(id & 255) << 24);
}

// ---------------- Kernel 1: normalize rows, emit i8 z (k-interleaved), pos --
// One row-pair per WAVE (4 pairs/block): no LDS, no barriers; lane holds
// 4 float4 per row, 6-round shuffle reduce for {|z1|^2, |z2|^2, z1.z2}.
// Column permutation within each 64-block (row-independent): a bijection on
// instruction-k applied to BOTH MFMA operands => cancels in the dot product.
__global__ __launch_bounds__(256) void norm_kernel(
    const float* __restrict__ p1, const float* __restrict__ p2,
    unsigned char* __restrict__ zq, float* __restrict__ pos)
{
    const int lane = threadIdx.x & 63;
    const int r    = blockIdx.x * 4 + (threadIdx.x >> 6);
    const float4* a = (const float4*)(p1 + (size_t)r * DIM);
    const float4* b = (const float4*)(p2 + (size_t)r * DIM);
    float4 x1[4], x2[4];
    float s1 = 0.0f, s2 = 0.0f, s12 = 0.0f;
#pragma unroll
    for (int v = 0; v < 4; ++v) {
        x1[v] = a[lane + (v << 6)];
        x2[v] = b[lane + (v << 6)];
        s1  += x1[v].x*x1[v].x + x1[v].y*x1[v].y + x1[v].z*x1[v].z + x1[v].w*x1[v].w;
        s2  += x2[v].x*x2[v].x + x2[v].y*x2[v].y + x2[v].z*x2[v].z + x2[v].w*x2[v].w;
        s12 += x1[v].x*x2[v].x + x1[v].y*x2[v].y + x1[v].z*x2[v].z + x1[v].w*x2[v].w;
    }
#pragma unroll
    for (int off = 1; off < 64; off <<= 1) {
        s1  += __shfl_xor(s1,  off);
        s2  += __shfl_xor(s2,  off);
        s12 += __shfl_xor(s12, off);
    }
    const float rn1 = 1.0f / fmaxf(sqrtf(s1), 1e-12f);
    const float rn2 = 1.0f / fmaxf(sqrtf(s2), 1e-12f);
    if (lane == 0) pos[r] = s12 * rn1 * rn2;

#pragma unroll
    for (int v = 0; v < 4; ++v) {
        const int fv = lane + (v << 6);          // float4 index in row
        const int j0 = (fv << 2) & 63;           // col within 64-block
        const int kb = fv >> 4;                  // 64-block index
        const int pb = (j0 < 32) ? (((j0 >> 3) << 4) + (j0 & 7))
                                 : ((((j0 - 32) >> 3) << 4) + 8 + ((j0 - 32) & 7));
        const size_t off8 = (size_t)kb * 64 + pb;
        *(unsigned int*)(zq + (size_t)r * DIM + off8) =
            pk4_i8(x1[v].x * rn1, x1[v].y * rn1, x1[v].z * rn1, x1[v].w * rn1);
        *(unsigned int*)(zq + (size_t)(NB + r) * DIM + off8) =
            pk4_i8(x2[v].x * rn2, x2[v].y * rn2, x2[v].z * rn2, x2[v].w * rn2);
    }
}

// ------- Kernel 2: i8 symmetric z.z^T; 512 full 256^2 tiles + 64 quarters ---
// R19-proven (54.8us): BK=128, 8 barrier phases, A+B staged in LDS with the
// 3-bit involution bank swizzle (linear gload dest + pre-swizzled global src
// + XOR'd ds_read; conflicts 31.7K). 64 quarter jobs backfill the tail.
__global__ __launch_bounds__(1024, 4) void sim_kernel(
    const unsigned char* __restrict__ zq,
    float* __restrict__ partials,    // [N2][PS], zeroed before launch
    float* __restrict__ lup)         // [NT2*NT2], full-tile rt<=ct slots
{
    __shared__ __align__(16) unsigned char buf[2][2][BT * 128]; // 128 KB
    const int t    = threadIdx.x;
    const int lane = t & 63;
    const int wid  = t >> 6;       // 0..15
    const int fr   = lane & 15;    // fragment row (A) / col (B)
    const int kg   = lane >> 4;    // k-group 0..3
    const int cb0  = ((kg ^ (fr & 7)) << 4);                 // h=0 swizzled slot
    const int sgr8 = (((lane & 7) ^ ((lane >> 3) & 7)) << 4); // involution src
    const int rsub = (lane >> 4) << 2;
    const int csub = lane & 15;
    const int bid = blockIdx.x;

    if (bid < GRID_FULL) {
        // ---------------- full 256x256 tile ----------------
        int jj = (bid & 7) * 64 + (bid >> 3);   // bijective XCD swizzle
#pragma unroll 1
        for (int k = 16; k < 32; ++k) {         // skip quartered diag tiles
            const int e = k * 32 - ((k * (k - 1)) >> 1);
            if (jj >= e) ++jj;
        }
        int rt = 0;
        while ((rt + 1) * 32 - (((rt + 1) * rt) >> 1) <= jj) ++rt;
        const int ct = rt + jj - (rt * 32 - ((rt * (rt - 1)) >> 1));
        const bool isdiag = (rt == ct);
        const int row0 = rt << 8;
        const int col0 = ct << 8;
        const int wr = wid >> 2;    // 0..3 (64-row strip)
        const int wc = wid & 3;     // 0..3 (64-col strip)

        const int abase = ((wr << 6) + fr) << 7;   // row stride 128
        const int bbase = ((wc << 6) + fr) << 7;

        // staging: 64 chunks of 8 rows x 128B (A: 0-31, B: 32-63), 4/wave;
        // lane l: row l>>3, LDS slot l&7 (linear), global granule sgr8
        const int ar0 = row0 + ((wid << 1) << 3) + (lane >> 3);
        const int br0 = col0 + ((wid << 1) << 3) + (lane >> 3);
        const unsigned char* asrc = zq + (size_t)ar0 * DIM + sgr8;
        const unsigned char* bsrc = zq + (size_t)br0 * DIM + sgr8;

#define STAGEF(bsel, kp) do { \
        gload_lds16(asrc + (kp) * 128,              &buf[bsel][0][(wid << 11)]); \
        gload_lds16(asrc + (size_t)8 * DIM + (kp) * 128, &buf[bsel][0][(wid << 11) + 1024]); \
        gload_lds16(bsrc + (kp) * 128,              &buf[bsel][1][(wid << 11)]); \
        gload_lds16(bsrc + (size_t)8 * DIM + (kp) * 128, &buf[bsel][1][(wid << 11) + 1024]); \
    } while (0)

        i32x4 acc[4][4] = {};
        STAGEF(0, 0);
        __syncthreads();

#pragma unroll
        for (int kp = 0; kp < 8; ++kp) {
            const int cur = kp & 1;
            if (kp < 7) STAGEF(cur ^ 1, kp + 1);
            const unsigned char* Ab = &buf[cur][0][0] + abase;
            const unsigned char* Bb = &buf[cur][1][0] + bbase;
#pragma unroll
            for (int h = 0; h < 2; ++h) {
                const int cbh = cb0 ^ (h << 6);
                i32x4 bq[4];
#pragma unroll
                for (int n = 0; n < 4; ++n)
                    bq[n] = *(const i32x4*)(Bb + (n << 11) + cbh);
#pragma unroll
                for (int m = 0; m < 4; ++m) {
                    const i32x4 aq = *(const i32x4*)(Ab + (m << 11) + cbh);
#pragma unroll
                    for (int n = 0; n < 4; ++n)
                        acc[m][n] = __builtin_amdgcn_mfma_i32_16x16x64_i8(aq, bq[n], acc[m][n], 0, 0, 0);
                }
            }
            __syncthreads();
        }
#undef STAGEF

        // ---- epilogue: C/D layout col=lane&15, row=(lane>>4)*4+reg ----
        float* rsum4 = (float*)&buf[0][0][0];   // [256][4] per-(row,wc)
        float* csum4 = rsum4 + 1024;            // [256][4] per-(col,wr)
        float* lured = csum4 + 1024;            // [16]
        const bool inreg = (ct < 8) || (rt >= 8 && ct < 16);  // lunif blocks
        const int  rbase = row0 + (wr << 6);
        const int  cbase = col0 + (wc << 6);

        float lu = 0.0f;
        float cs[4] = {0.0f, 0.0f, 0.0f, 0.0f};
#pragma unroll
        for (int m = 0; m < 4; ++m) {
            float rs[4] = {0.0f, 0.0f, 0.0f, 0.0f};
#pragma unroll
            for (int n = 0; n < 4; ++n) {
                const int gcol = cbase + (n << 4) + csub;
#pragma unroll
                for (int r = 0; r < 4; ++r) {
                    const int grow = rbase + (m << 4) + rsub + r;
                    const float f = (float)acc[m][n][r];
                    float e = exp2f(f * C1f);
                    if (isdiag) e = (grow != gcol) ? e : 0.0f;
                    rs[r] += e;
                    cs[n] += e;
                    if (inreg && (!isdiag || gcol > grow))
                        lu += exp2f(fmaf(f, C2f, C2b));
                }
            }
#pragma unroll
            for (int off = 1; off < 16; off <<= 1) {
#pragma unroll
                for (int r = 0; r < 4; ++r) rs[r] += __shfl_xor(rs[r], off);
            }
            if ((lane & 15) == 0) {
#pragma unroll
                for (int r = 0; r < 4; ++r)
                    rsum4[((wr << 6) + (m << 4) + rsub + r) * 4 + wc] = rs[r];
            }
        }
        if (!isdiag) {
#pragma unroll
            for (int off = 16; off < 64; off <<= 1) {
#pragma unroll
                for (int n = 0; n < 4; ++n) cs[n] += __shfl_xor(cs[n], off);
            }
            if (lane < 16) {
#pragma unroll
                for (int n = 0; n < 4; ++n)
                    csum4[((wc << 6) + (n << 4) + lane) * 4 + wr] = cs[n];
            }
        }
#pragma unroll
        for (int off = 1; off < 64; off <<= 1) lu += __shfl_xor(lu, off);
        if (lane == 0) lured[wid] = lu;
        __syncthreads();

        if (t == 0) {
            float s = 0.0f;
#pragma unroll
            for (int w = 0; w < 16; ++w) s += lured[w];
            lup[rt * NT2 + ct] = s;
        }
        if (t < 256) {
            const float* p = rsum4 + t * 4;
            partials[(size_t)(row0 + t) * PS + ct] = ((p[0] + p[1]) + p[2]) + p[3];
        } else if (t < 512 && !isdiag) {
            const float* p = csum4 + (t - 256) * 4;
            partials[(size_t)(col0 + t - 256) * PS + rt] = ((p[0] + p[1]) + p[2]) + p[3];
        }
    } else {
        // ------------- quarter 128x128 of diag tile (k,k), k=16..31 --------
        const int q  = bid - GRID_FULL;
        const int k  = 16 + (q >> 2);
        const int qr = (q >> 1) & 1;
        const int qc = q & 1;
        const int row0 = (k << 8) + (qr << 7);
        const int col0 = (k << 8) + (qc << 7);
        const int wr = wid >> 2;    // 0..3 (32-row strip)
        const int wc = wid & 3;     // 0..3 (32-col strip)

        // staging: 32 chunks of 8 rows (A: 0-15, B: 16-31), 2 per wave
        const int ch  = wid << 1;
        const int isB = ch >> 4;
        const int chl = ch & 15;
        const unsigned char* spanel =
            zq + (size_t)((isB ? col0 : row0) + (chl << 3) + (lane >> 3)) * DIM + sgr8;
        unsigned char* d0a = &buf[0][isB][chl << 10];
        unsigned char* d1a = &buf[1][isB][chl << 10];

        i32x4 acc[2][2] = {};
        gload_lds16(spanel, d0a);
        gload_lds16(spanel + (size_t)8 * DIM, d0a + 1024);
        __syncthreads();

#pragma unroll
        for (int kp = 0; kp < 8; ++kp) {
            const int cur = kp & 1;
            if (kp < 7) {
                unsigned char* dn = cur ? d0a : d1a;
                gload_lds16(spanel + (kp + 1) * 128, dn);
                gload_lds16(spanel + (size_t)8 * DIM + (kp + 1) * 128, dn + 1024);
            }
            const unsigned char* Ab = &buf[cur][0][0] + (((wr << 5) + fr) << 7);
            const unsigned char* Bb = &buf[cur][1][0] + (((wc << 5) + fr) << 7);
#pragma unroll
            for (int h = 0; h < 2; ++h) {
                const int cbh = cb0 ^ (h << 6);
                i32x4 aq[2], bq[2];
#pragma unroll
                for (int n = 0; n < 2; ++n)
                    bq[n] = *(const i32x4*)(Bb + (n << 11) + cbh);
#pragma unroll
                for (int m = 0; m < 2; ++m)
                    aq[m] = *(const i32x4*)(Ab + (m << 11) + cbh);
#pragma unroll
                for (int m = 0; m < 2; ++m)
#pragma unroll
                    for (int n = 0; n < 2; ++n)
                        acc[m][n] = __builtin_amdgcn_mfma_i32_16x16x64_i8(aq[m], bq[n], acc[m][n], 0, 0, 0);
            }
            __syncthreads();
        }

        // epilogue: rowsum only (z_j diag region: no colsum, no lunif)
        float* rsum4 = (float*)&buf[0][0][0];   // [128][4] per-(row,wc)
#pragma unroll
        for (int m = 0; m < 2; ++m) {
            float rs[4] = {0.0f, 0.0f, 0.0f, 0.0f};
#pragma unroll
            for (int n = 0; n < 2; ++n) {
                const int gcol = col0 + (wc << 5) + (n << 4) + csub;
#pragma unroll
                for (int r = 0; r < 4; ++r) {
                    const int grow = row0 + (wr << 5) + (m << 4) + rsub + r;
                    float e = exp2f((float)acc[m][n][r] * C1f);
                    e = (grow != gcol) ? e : 0.0f;   // diag mask (qr==qc quads)
                    rs[r] += e;
                }
            }
#pragma unroll
            for (int off = 1; off < 16; off <<= 1) {
#pragma unroll
                for (int r = 0; r < 4; ++r) rs[r] += __shfl_xor(rs[r], off);
            }
            if ((lane & 15) == 0) {
#pragma unroll
                for (int r = 0; r < 4; ++r)
                    rsum4[((wr << 5) + (m << 4) + rsub + r) * 4 + wc] = rs[r];
            }
        }
        __syncthreads();
        if (t < 128) {
            const float* p = rsum4 + t * 4;
            partials[(size_t)(row0 + t) * PS + (qc ? 32 : k)] =
                ((p[0] + p[1]) + p[2]) + p[3];
        }
    }
}

// --------- Kernel 3a: per-row denom -> log; also pre-reduce pos -------------
__global__ __launch_bounds__(128) void logred_kernel(
    const float* __restrict__ partials, const float* __restrict__ pos,
    double* __restrict__ red_log, double* __restrict__ red_pos)
{
    const int t   = threadIdx.x;
    const int row = blockIdx.x * 128 + t;
    const float* p = partials + (size_t)row * PS;
    float dsum = 0.0f;
#pragma unroll
    for (int i = 0; i < 33; ++i) dsum += p[i];   // 32 main + aux slot 32
    double l = log((double)dsum);
    __shared__ double sd[128];
    sd[t] = l;
    __syncthreads();
    for (int s = 64; s > 0; s >>= 1) {
        if (t < s) sd[t] += sd[t + s];
        __syncthreads();
    }
    if (t == 0) red_log[blockIdx.x] = sd[0];
    __syncthreads();
    // pos slice: 64 entries per block (NB/64 blocks worth over 64 blocks)
    sd[t] = (t < 64) ? (double)pos[blockIdx.x * 64 + t] : 0.0;
    __syncthreads();
    for (int s = 32; s > 0; s >>= 1) {
        if (t < s) sd[t] += sd[t + s];
        __syncthreads();
    }
    if (t == 0) red_pos[blockIdx.x] = sd[0];
}

// --------- Kernel 3b: final scalars --------------------------------------
__global__ __launch_bounds__(256) void final_kernel(
    const double* __restrict__ red_log, const double* __restrict__ red_pos,
    const float* __restrict__ lup, float* __restrict__ out)
{
    const int t = threadIdx.x;
    double dlog = 0.0, dpos = 0.0, ds1 = 0.0, ds2 = 0.0;
    if (t < 64) { dlog = red_log[t]; dpos = red_pos[t]; }
    for (int i = t; i < NT2 * NT2; i += 256) {
        const int rt = i >> 5, ct = i & 31;
        if (rt > ct) continue;                 // only upper-tri tiles written
        const double v = (double)lup[i];
        if (rt < 8 && ct < 8) ds1 += v;
        else if (rt >= 8 && rt < 16 && ct >= 8 && ct < 16) ds2 += v;
    }
    __shared__ double sd[4][256];
    sd[0][t] = dlog; sd[1][t] = dpos; sd[2][t] = ds1; sd[3][t] = ds2;
    __syncthreads();
    for (int s = 128; s > 0; s >>= 1) {
        if (t < s) {
            sd[0][t] += sd[0][t + s]; sd[1][t] += sd[1][t + s];
            sd[2][t] += sd[2][t + s]; sd[3][t] += sd[3][t + s];
        }
        __syncthreads();
    }
    if (t == 0) {
        const double mean_pos = sd[1][0] / (double)NB;
        const double loss   = sd[0][0] / (double)N2 - mean_pos * 10.0;   // /TEMP
        const double lalign = 2.0 - 2.0 * mean_pos;
        const double C      = 2048.0 * 2047.0 * 0.5;
        const double lunif  = 0.5 * (log(sd[2][0] / C) + log(sd[3][0] / C));
        out[0] = (float)loss;
        out[1] = (float)lalign;
        out[2] = (float)lunif;
    }
}

extern "C" void kernel_launch(void* const* d_in, const int* in_sizes, int n_in,
                              void* d_out, int out_size, void* d_ws, size_t ws_size,
                              hipStream_t stream) {
    const float* p1 = (const float*)d_in[0];
    const float* p2 = (const float*)d_in[1];
    float* out = (float*)d_out;

    char* ws = (char*)d_ws;
    unsigned char* zq = (unsigned char*)ws;                              // 8 MB
    float*  partials  = (float*)(ws + ((size_t)8 << 20));                // ~1.1 MB [8192][34]
    float*  pos       = (float*)(ws + ((size_t)10 << 20));               // 16 KB
    float*  lup       = (float*)(ws + ((size_t)10 << 20) + 16384);       // 4 KB
    double* red_log   = (double*)(ws + ((size_t)10 << 20) + 16384 + 4096);  // 512 B
    double* red_pos   = (double*)(ws + ((size_t)10 << 20) + 16384 + 4096 + 512); // 512 B

    hipMemsetAsync(partials, 0, (size_t)N2 * PS * sizeof(float), stream);
    hipLaunchKernelGGL(norm_kernel,   dim3(NB / 4),   dim3(256),  0, stream, p1, p2, zq, pos);
    hipLaunchKernelGGL(sim_kernel,    dim3(GRID_ALL), dim3(1024), 0, stream, zq, partials, lup);
    hipLaunchKernelGGL(logred_kernel, dim3(64),       dim3(128),  0, stream, partials, pos, red_log, red_pos);
    hipLaunchKernelGGL(final_kernel,  dim3(1),        dim3(256),  0, stream, red_log, red_pos, lup, out);
}

// Round 22
// 75.321 us; speedup vs baseline: 1.7443x; 1.0022x over previous
//
#include <hip/hip_runtime.h>
#include <hip/hip_bf16.h>
#include <math.h>

#define DIM 1024
#define NB  4096      // B
#define N2  8192      // 2B
#define BT  256       // full tile dim
#define NT2 32        // N2 / BT
#define PS  34        // partials stride: 32 col-tile slots + aux + pad
#define GRID_FULL 512 // 528 tiles - 16 quartered diagonals
#define GRID_ALL  576 // + 64 quarter jobs

#define C1f 8.9447146e-4f    // 10*log2(e)/127^2
#define C2f 3.5778876e-4f    // 4*log2(e)/127^2
#define C2b (-5.7707802f)    // -4*log2(e)

typedef int i32x4 __attribute__((ext_vector_type(4)));

__device__ __forceinline__ void gload_lds16(const unsigned char* g, unsigned char* l) {
    __builtin_amdgcn_global_load_lds((__attribute__((address_space(1))) void*)(g),
                                     (__attribute__((address_space(3))) void*)(l),
                                     16, 0, 0);
}

// sum across a 16-lane DPP row via row_ror {1,2,4,8} — VALU pipe, not LDS.
// Replaces 4x shfl_xor(ds_bpermute): rotations within the row sum all 16.
__device__ __forceinline__ float rowsum16(float s) {
    int v;
    v = __builtin_amdgcn_update_dpp(0, __builtin_bit_cast(int, s), 0x121, 0xf, 0xf, true);
    s += __builtin_bit_cast(float, v);
    v = __builtin_amdgcn_update_dpp(0, __builtin_bit_cast(int, s), 0x122, 0xf, 0xf, true);
    s += __builtin_bit_cast(float, v);
    v = __builtin_amdgcn_update_dpp(0, __builtin_bit_cast(int, s), 0x124, 0xf, 0xf, true);
    s += __builtin_bit_cast(float, v);
    v = __builtin_amdgcn_update_dpp(0, __builtin_bit_cast(int, s), 0x128, 0xf, 0xf, true);
    s += __builtin_bit_cast(float, v);
    return s;
}

// pack 4 int8 (round-to-nearest of x*127; |x|<=1 so no clamp needed)
__device__ __forceinline__ unsigned int pk4_i8(float a, float b, float c, float d) {
    const int ia = __float2int_rn(a * 127.0f), ib = __float2int_rn(b * 127.0f);
    const int ic = __float2int_rn(c * 127.0f), id = __float2int_rn(d * 127.0f);
    return (unsigned)(ia & 255) | ((unsigned)(ib & 255) << 8) |
           ((unsigned)(ic & 255) << 16) | ((unsigned)(id & 255) << 24);
}

// ---------------- Kernel 1: normalize rows, emit i8 z (k-interleaved), pos --
// One row-pair per WAVE (4 pairs/block): no LDS, no barriers.
__global__ __launch_bounds__(256) void norm_kernel(
    const float* __restrict__ p1, const float* __restrict__ p2,
    unsigned char* __restrict__ zq, float* __restrict__ pos)
{
    const int lane = threadIdx.x & 63;
    const int r    = blockIdx.x * 4 + (threadIdx.x >> 6);
    const float4* a = (const float4*)(p1 + (size_t)r * DIM);
    const float4* b = (const float4*)(p2 + (size_t)r * DIM);
    float4 x1[4], x2[4];
    float s1 = 0.0f, s2 = 0.0f, s12 = 0.0f;
#pragma unroll
    for (int v = 0; v < 4; ++v) {
        x1[v] = a[lane + (v << 6)];
        x2[v] = b[lane + (v << 6)];
        s1  += x1[v].x*x1[v].x + x1[v].y*x1[v].y + x1[v].z*x1[v].z + x1[v].w*x1[v].w;
        s2  += x2[v].x*x2[v].x + x2[v].y*x2[v].y + x2[v].z*x2[v].z + x2[v].w*x2[v].w;
        s12 += x1[v].x*x2[v].x + x1[v].y*x2[v].y + x1[v].z*x2[v].z + x1[v].w*x2[v].w;
    }
#pragma unroll
    for (int off = 1; off < 64; off <<= 1) {
        s1  += __shfl_xor(s1,  off);
        s2  += __shfl_xor(s2,  off);
        s12 += __shfl_xor(s12, off);
    }
    const float rn1 = 1.0f / fmaxf(sqrtf(s1), 1e-12f);
    const float rn2 = 1.0f / fmaxf(sqrtf(s2), 1e-12f);
    if (lane == 0) pos[r] = s12 * rn1 * rn2;

#pragma unroll
    for (int v = 0; v < 4; ++v) {
        const int fv = lane + (v << 6);          // float4 index in row
        const int j0 = (fv << 2) & 63;           // col within 64-block
        const int kb = fv >> 4;                  // 64-block index
        const int pb = (j0 < 32) ? (((j0 >> 3) << 4) + (j0 & 7))
                                 : ((((j0 - 32) >> 3) << 4) + 8 + ((j0 - 32) & 7));
        const size_t off8 = (size_t)kb * 64 + pb;
        *(unsigned int*)(zq + (size_t)r * DIM + off8) =
            pk4_i8(x1[v].x * rn1, x1[v].y * rn1, x1[v].z * rn1, x1[v].w * rn1);
        *(unsigned int*)(zq + (size_t)(NB + r) * DIM + off8) =
            pk4_i8(x2[v].x * rn2, x2[v].y * rn2, x2[v].z * rn2, x2[v].w * rn2);
    }
}

// ------- Kernel 2: i8 symmetric z.z^T; 512 full 256^2 tiles + 64 quarters ---
// R19/R21 structure (sim 55us) + DPP rowsum reductions (moves ~12k cyc/job of
// ds_bpermute traffic off the binding LDS pipe onto the VALU).
__global__ __launch_bounds__(1024, 4) void sim_kernel(
    const unsigned char* __restrict__ zq,
    float* __restrict__ partials,    // [N2][PS], zeroed before launch
    float* __restrict__ lup)         // [NT2*NT2], full-tile rt<=ct slots
{
    __shared__ __align__(16) unsigned char buf[2][2][BT * 128]; // 128 KB
    const int t    = threadIdx.x;
    const int lane = t & 63;
    const int wid  = t >> 6;       // 0..15
    const int fr   = lane & 15;    // fragment row (A) / col (B)
    const int kg   = lane >> 4;    // k-group 0..3
    const int cb0  = ((kg ^ (fr & 7)) << 4);                 // h=0 swizzled slot
    const int sgr8 = (((lane & 7) ^ ((lane >> 3) & 7)) << 4); // involution src
    const int rsub = (lane >> 4) << 2;
    const int csub = lane & 15;
    const int bid = blockIdx.x;

    if (bid < GRID_FULL) {
        // ---------------- full 256x256 tile ----------------
        int jj = (bid & 7) * 64 + (bid >> 3);   // bijective XCD swizzle
#pragma unroll 1
        for (int k = 16; k < 32; ++k) {         // skip quartered diag tiles
            const int e = k * 32 - ((k * (k - 1)) >> 1);
            if (jj >= e) ++jj;
        }
        int rt = 0;
        while ((rt + 1) * 32 - (((rt + 1) * rt) >> 1) <= jj) ++rt;
        const int ct = rt + jj - (rt * 32 - ((rt * (rt - 1)) >> 1));
        const bool isdiag = (rt == ct);
        const int row0 = rt << 8;
        const int col0 = ct << 8;
        const int wr = wid >> 2;    // 0..3 (64-row strip)
        const int wc = wid & 3;     // 0..3 (64-col strip)

        const int abase = ((wr << 6) + fr) << 7;   // row stride 128
        const int bbase = ((wc << 6) + fr) << 7;

        // staging: 64 chunks of 8 rows x 128B (A: 0-31, B: 32-63), 4/wave;
        // lane l: row l>>3, LDS slot l&7 (linear), global granule sgr8
        const int ar0 = row0 + ((wid << 1) << 3) + (lane >> 3);
        const int br0 = col0 + ((wid << 1) << 3) + (lane >> 3);
        const unsigned char* asrc = zq + (size_t)ar0 * DIM + sgr8;
        const unsigned char* bsrc = zq + (size_t)br0 * DIM + sgr8;

#define STAGEF(bsel, kp) do { \
        gload_lds16(asrc + (kp) * 128,              &buf[bsel][0][(wid << 11)]); \
        gload_lds16(asrc + (size_t)8 * DIM + (kp) * 128, &buf[bsel][0][(wid << 11) + 1024]); \
        gload_lds16(bsrc + (kp) * 128,              &buf[bsel][1][(wid << 11)]); \
        gload_lds16(bsrc + (size_t)8 * DIM + (kp) * 128, &buf[bsel][1][(wid << 11) + 1024]); \
    } while (0)

        i32x4 acc[4][4] = {};
        STAGEF(0, 0);
        __syncthreads();

#pragma unroll
        for (int kp = 0; kp < 8; ++kp) {
            const int cur = kp & 1;
            if (kp < 7) STAGEF(cur ^ 1, kp + 1);
            const unsigned char* Ab = &buf[cur][0][0] + abase;
            const unsigned char* Bb = &buf[cur][1][0] + bbase;
#pragma unroll
            for (int h = 0; h < 2; ++h) {
                const int cbh = cb0 ^ (h << 6);
                i32x4 bq[4];
#pragma unroll
                for (int n = 0; n < 4; ++n)
                    bq[n] = *(const i32x4*)(Bb + (n << 11) + cbh);
#pragma unroll
                for (int m = 0; m < 4; ++m) {
                    const i32x4 aq = *(const i32x4*)(Ab + (m << 11) + cbh);
#pragma unroll
                    for (int n = 0; n < 4; ++n)
                        acc[m][n] = __builtin_amdgcn_mfma_i32_16x16x64_i8(aq, bq[n], acc[m][n], 0, 0, 0);
                }
            }
            __syncthreads();
        }
#undef STAGEF

        // ---- epilogue: C/D layout col=lane&15, row=(lane>>4)*4+reg ----
        float* rsum4 = (float*)&buf[0][0][0];   // [256][4] per-(row,wc)
        float* csum4 = rsum4 + 1024;            // [256][4] per-(col,wr)
        float* lured = csum4 + 1024;            // [16]
        const bool inreg = (ct < 8) || (rt >= 8 && ct < 16);  // lunif blocks
        const int  rbase = row0 + (wr << 6);
        const int  cbase = col0 + (wc << 6);

        float lu = 0.0f;
        float cs[4] = {0.0f, 0.0f, 0.0f, 0.0f};
#pragma unroll
        for (int m = 0; m < 4; ++m) {
            float rs[4] = {0.0f, 0.0f, 0.0f, 0.0f};
#pragma unroll
            for (int n = 0; n < 4; ++n) {
                const int gcol = cbase + (n << 4) + csub;
#pragma unroll
                for (int r = 0; r < 4; ++r) {
                    const int grow = rbase + (m << 4) + rsub + r;
                    const float f = (float)acc[m][n][r];
                    float e = exp2f(f * C1f);
                    if (isdiag) e = (grow != gcol) ? e : 0.0f;
                    rs[r] += e;
                    cs[n] += e;
                    if (inreg && (!isdiag || gcol > grow))
                        lu += exp2f(fmaf(f, C2f, C2b));
                }
            }
#pragma unroll
            for (int r = 0; r < 4; ++r) rs[r] = rowsum16(rs[r]);   // DPP, VALU pipe
            if ((lane & 15) == 0) {
#pragma unroll
                for (int r = 0; r < 4; ++r)
                    rsum4[((wr << 6) + (m << 4) + rsub + r) * 4 + wc] = rs[r];
            }
        }
        if (!isdiag) {
#pragma unroll
            for (int off = 16; off < 64; off <<= 1) {
#pragma unroll
                for (int n = 0; n < 4; ++n) cs[n] += __shfl_xor(cs[n], off);
            }
            if (lane < 16) {
#pragma unroll
                for (int n = 0; n < 4; ++n)
                    csum4[((wc << 6) + (n << 4) + lane) * 4 + wr] = cs[n];
            }
        }
        lu = rowsum16(lu);
        lu += __shfl_xor(lu, 16);
        lu += __shfl_xor(lu, 32);
        if (lane == 0) lured[wid] = lu;
        __syncthreads();

        if (t == 0) {
            float s = 0.0f;
#pragma unroll
            for (int w = 0; w < 16; ++w) s += lured[w];
            lup[rt * NT2 + ct] = s;
        }
        if (t < 256) {
            const float* p = rsum4 + t * 4;
            partials[(size_t)(row0 + t) * PS + ct] = ((p[0] + p[1]) + p[2]) + p[3];
        } else if (t < 512 && !isdiag) {
            const float* p = csum4 + (t - 256) * 4;
            partials[(size_t)(col0 + t - 256) * PS + rt] = ((p[0] + p[1]) + p[2]) + p[3];
        }
    } else {
        // ------------- quarter 128x128 of diag tile (k,k), k=16..31 --------
        const int q  = bid - GRID_FULL;
        const int k  = 16 + (q >> 2);
        const int qr = (q >> 1) & 1;
        const int qc = q & 1;
        const int row0 = (k << 8) + (qr << 7);
        const int col0 = (k << 8) + (qc << 7);
        const int wr = wid >> 2;    // 0..3 (32-row strip)
        const int wc = wid & 3;     // 0..3 (32-col strip)

        // staging: 32 chunks of 8 rows (A: 0-15, B: 16-31), 2 per wave
        const int ch  = wid << 1;
        const int isB = ch >> 4;
        const int chl = ch & 15;
        const unsigned char* spanel =
            zq + (size_t)((isB ? col0 : row0) + (chl << 3) + (lane >> 3)) * DIM + sgr8;
        unsigned char* d0a = &buf[0][isB][chl << 10];
        unsigned char* d1a = &buf[1][isB][chl << 10];

        i32x4 acc[2][2] = {};
        gload_lds16(spanel, d0a);
        gload_lds16(spanel + (size_t)8 * DIM, d0a + 1024);
        __syncthreads();

#pragma unroll
        for (int kp = 0; kp < 8; ++kp) {
            const int cur = kp & 1;
            if (kp < 7) {
                unsigned char* dn = cur ? d0a : d1a;
                gload_lds16(spanel + (kp + 1) * 128, dn);
                gload_lds16(spanel + (size_t)8 * DIM + (kp + 1) * 128, dn + 1024);
            }
            const unsigned char* Ab = &buf[cur][0][0] + (((wr << 5) + fr) << 7);
            const unsigned char* Bb = &buf[cur][1][0] + (((wc << 5) + fr) << 7);
#pragma unroll
            for (int h = 0; h < 2; ++h) {
                const int cbh = cb0 ^ (h << 6);
                i32x4 aq[2], bq[2];
#pragma unroll
                for (int n = 0; n < 2; ++n)
                    bq[n] = *(const i32x4*)(Bb + (n << 11) + cbh);
#pragma unroll
                for (int m = 0; m < 2; ++m)
                    aq[m] = *(const i32x4*)(Ab + (m << 11) + cbh);
#pragma unroll
                for (int m = 0; m < 2; ++m)
#pragma unroll
                    for (int n = 0; n < 2; ++n)
                        acc[m][n] = __builtin_amdgcn_mfma_i32_16x16x64_i8(aq[m], bq[n], acc[m][n], 0, 0, 0);
            }
            __syncthreads();
        }

        // epilogue: rowsum only (z_j diag region: no colsum, no lunif)
        float* rsum4 = (float*)&buf[0][0][0];   // [128][4] per-(row,wc)
#pragma unroll
        for (int m = 0; m < 2; ++m) {
            float rs[4] = {0.0f, 0.0f, 0.0f, 0.0f};
#pragma unroll
            for (int n = 0; n < 2; ++n) {
                const int gcol = col0 + (wc << 5) + (n << 4) + csub;
#pragma unroll
                for (int r = 0; r < 4; ++r) {
                    const int grow = row0 + (wr << 5) + (m << 4) + rsub + r;
                    float e = exp2f((float)acc[m][n][r] * C1f);
                    e = (grow != gcol) ? e : 0.0f;   // diag mask (qr==qc quads)
                    rs[r] += e;
                }
            }
#pragma unroll
            for (int r = 0; r < 4; ++r) rs[r] = rowsum16(rs[r]);   // DPP
            if ((lane & 15) == 0) {
#pragma unroll
                for (int r = 0; r < 4; ++r)
                    rsum4[((wr << 5) + (m << 4) + rsub + r) * 4 + wc] = rs[r];
            }
        }
        __syncthreads();
        if (t < 128) {
            const float* p = rsum4 + t * 4;
            partials[(size_t)(row0 + t) * PS + (qc ? 32 : k)] =
                ((p[0] + p[1]) + p[2]) + p[3];
        }
    }
}

// --------- Kernel 3a: per-row denom -> log; also pre-reduce pos -------------
__global__ __launch_bounds__(128) void logred_kernel(
    const float* __restrict__ partials, const float* __restrict__ pos,
    double* __restrict__ red_log, double* __restrict__ red_pos)
{
    const int t   = threadIdx.x;
    const int row = blockIdx.x * 128 + t;
    const float* p = partials + (size_t)row * PS;
    float dsum = 0.0f;
#pragma unroll
    for (int i = 0; i < 33; ++i) dsum += p[i];   // 32 main + aux slot 32
    double l = log((double)dsum);
    __shared__ double sd[128];
    sd[t] = l;
    __syncthreads();
    for (int s = 64; s > 0; s >>= 1) {
        if (t < s) sd[t] += sd[t + s];
        __syncthreads();
    }
    if (t == 0) red_log[blockIdx.x] = sd[0];
    __syncthreads();
    sd[t] = (t < 64) ? (double)pos[blockIdx.x * 64 + t] : 0.0;
    __syncthreads();
    for (int s = 32; s > 0; s >>= 1) {
        if (t < s) sd[t] += sd[t + s];
        __syncthreads();
    }
    if (t == 0) red_pos[blockIdx.x] = sd[0];
}

// --------- Kernel 3b: final scalars --------------------------------------
__global__ __launch_bounds__(256) void final_kernel(
    const double* __restrict__ red_log, const double* __restrict__ red_pos,
    const float* __restrict__ lup, float* __restrict__ out)
{
    const int t = threadIdx.x;
    double dlog = 0.0, dpos = 0.0, ds1 = 0.0, ds2 = 0.0;
    if (t < 64) { dlog = red_log[t]; dpos = red_pos[t]; }
    for (int i = t; i < NT2 * NT2; i += 256) {
        const int rt = i >> 5, ct = i & 31;
        if (rt > ct) continue;                 // only upper-tri tiles written
        const double v = (double)lup[i];
        if (rt < 8 && ct < 8) ds1 += v;
        else if (rt >= 8 && rt < 16 && ct >= 8 && ct < 16) ds2 += v;
    }
    __shared__ double sd[4][256];
    sd[0][t] = dlog; sd[1][t] = dpos; sd[2][t] = ds1; sd[3][t] = ds2;
    __syncthreads();
    for (int s = 128; s > 0; s >>= 1) {
        if (t < s) {
            sd[0][t] += sd[0][t + s]; sd[1][t] += sd[1][t + s];
            sd[2][t] += sd[2][t + s]; sd[3][t] += sd[3][t + s];
        }
        __syncthreads();
    }
    if (t == 0) {
        const double mean_pos = sd[1][0] / (double)NB;
        const double loss   = sd[0][0] / (double)N2 - mean_pos * 10.0;   // /TEMP
        const double lalign = 2.0 - 2.0 * mean_pos;
        const double C      = 2048.0 * 2047.0 * 0.5;
        const double lunif  = 0.5 * (log(sd[2][0] / C) + log(sd[3][0] / C));
        out[0] = (float)loss;
        out[1] = (float)lalign;
        out[2] = (float)lunif;
    }
}

extern "C" void kernel_launch(void* const* d_in, const int* in_sizes, int n_in,
                              void* d_out, int out_size, void* d_ws, size_t ws_size,
                              hipStream_t stream) {
    const float* p1 = (const float*)d_in[0];
    const float* p2 = (const float*)d_in[1];
    float* out = (float*)d_out;

    char* ws = (char*)d_ws;
    unsigned char* zq = (unsigned char*)ws;                              // 8 MB
    float*  partials  = (float*)(ws + ((size_t)8 << 20));                // ~1.1 MB [8192][34]
    float*  pos       = (float*)(ws + ((size_t)10 << 20));               // 16 KB
    float*  lup       = (float*)(ws + ((size_t)10 << 20) + 16384);       // 4 KB
    double* red_log   = (double*)(ws + ((size_t)10 << 20) + 16384 + 4096);  // 512 B
    double* red_pos   = (double*)(ws + ((size_t)10 << 20) + 16384 + 4096 + 512); // 512 B

    hipMemsetAsync(partials, 0, (size_t)N2 * PS * sizeof(float), stream);
    hipLaunchKernelGGL(norm_kernel,   dim3(NB / 4),   dim3(256),  0, stream, p1, p2, zq, pos);
    hipLaunchKernelGGL(sim_kernel,    dim3(GRID_ALL), dim3(1024), 0, stream, zq, partials, lup);
    hipLaunchKernelGGL(logred_kernel, dim3(64),       dim3(128),  0, stream, partials, pos, red_log, red_pos);
    hipLaunchKernelGGL(final_kernel,  dim3(1),        dim3(256),  0, stream, red_log, red_pos, lup, out);
}

// Round 23
// 70.431 us; speedup vs baseline: 1.8654x; 1.0694x over previous
//
#include <hip/hip_runtime.h>
#include <hip/hip_bf16.h>
#include <math.h>

#define DIM 1024
#define NB  4096      // B
#define N2  8192      // 2B
#define BT  256       // full tile dim
#define NT2 32        // N2 / BT
#define PS  34        // partials stride: 32 col-tile slots + aux + pad
#define GRID_FULL 512 // 528 tiles - 16 quartered diagonals
#define GRID_ALL  576 // + 64 quarter jobs

#define C1f 8.9447146e-4f    // 10*log2(e)/127^2
#define C2f 3.5778876e-4f    // 4*log2(e)/127^2
#define C2b (-5.7707802f)    // -4*log2(e)

typedef int i32x4 __attribute__((ext_vector_type(4)));

__device__ __forceinline__ void gload_lds16(const unsigned char* g, unsigned char* l) {
    __builtin_amdgcn_global_load_lds((__attribute__((address_space(1))) void*)(g),
                                     (__attribute__((address_space(3))) void*)(l),
                                     16, 0, 0);
}

// sum across a 16-lane DPP row via row_ror {1,2,4,8} — VALU pipe, not LDS.
__device__ __forceinline__ float rowsum16(float s) {
    int v;
    v = __builtin_amdgcn_update_dpp(0, __builtin_bit_cast(int, s), 0x121, 0xf, 0xf, true);
    s += __builtin_bit_cast(float, v);
    v = __builtin_amdgcn_update_dpp(0, __builtin_bit_cast(int, s), 0x122, 0xf, 0xf, true);
    s += __builtin_bit_cast(float, v);
    v = __builtin_amdgcn_update_dpp(0, __builtin_bit_cast(int, s), 0x124, 0xf, 0xf, true);
    s += __builtin_bit_cast(float, v);
    v = __builtin_amdgcn_update_dpp(0, __builtin_bit_cast(int, s), 0x128, 0xf, 0xf, true);
    s += __builtin_bit_cast(float, v);
    return s;
}

// pack 4 int8 (round-to-nearest of x*127; |x|<=1 so no clamp needed)
__device__ __forceinline__ unsigned int pk4_i8(float a, float b, float c, float d) {
    const int ia = __float2int_rn(a * 127.0f), ib = __float2int_rn(b * 127.0f);
    const int ic = __float2int_rn(c * 127.0f), id = __float2int_rn(d * 127.0f);
    return (unsigned)(ia & 255) | ((unsigned)(ib & 255) << 8) |
           ((unsigned)(ic & 255) << 16) | ((unsigned)(id & 255) << 24);
}

// ---------------- Kernel 1: normalize rows, emit i8 z (k-interleaved), pos --
// One row-pair per WAVE (4 pairs/block): no LDS, no barriers.
__global__ __launch_bounds__(256) void norm_kernel(
    const float* __restrict__ p1, const float* __restrict__ p2,
    unsigned char* __restrict__ zq, float* __restrict__ pos)
{
    const int lane = threadIdx.x & 63;
    const int r    = blockIdx.x * 4 + (threadIdx.x >> 6);
    const float4* a = (const float4*)(p1 + (size_t)r * DIM);
    const float4* b = (const float4*)(p2 + (size_t)r * DIM);
    float4 x1[4], x2[4];
    float s1 = 0.0f, s2 = 0.0f, s12 = 0.0f;
#pragma unroll
    for (int v = 0; v < 4; ++v) {
        x1[v] = a[lane + (v << 6)];
        x2[v] = b[lane + (v << 6)];
        s1  += x1[v].x*x1[v].x + x1[v].y*x1[v].y + x1[v].z*x1[v].z + x1[v].w*x1[v].w;
        s2  += x2[v].x*x2[v].x + x2[v].y*x2[v].y + x2[v].z*x2[v].z + x2[v].w*x2[v].w;
        s12 += x1[v].x*x2[v].x + x1[v].y*x2[v].y + x1[v].z*x2[v].z + x1[v].w*x2[v].w;
    }
#pragma unroll
    for (int off = 1; off < 64; off <<= 1) {
        s1  += __shfl_xor(s1,  off);
        s2  += __shfl_xor(s2,  off);
        s12 += __shfl_xor(s12, off);
    }
    const float rn1 = 1.0f / fmaxf(sqrtf(s1), 1e-12f);
    const float rn2 = 1.0f / fmaxf(sqrtf(s2), 1e-12f);
    if (lane == 0) pos[r] = s12 * rn1 * rn2;

#pragma unroll
    for (int v = 0; v < 4; ++v) {
        const int fv = lane + (v << 6);          // float4 index in row
        const int j0 = (fv << 2) & 63;           // col within 64-block
        const int kb = fv >> 4;                  // 64-block index
        const int pb = (j0 < 32) ? (((j0 >> 3) << 4) + (j0 & 7))
                                 : ((((j0 - 32) >> 3) << 4) + 8 + ((j0 - 32) & 7));
        const size_t off8 = (size_t)kb * 64 + pb;
        *(unsigned int*)(zq + (size_t)r * DIM + off8) =
            pk4_i8(x1[v].x * rn1, x1[v].y * rn1, x1[v].z * rn1, x1[v].w * rn1);
        *(unsigned int*)(zq + (size_t)(NB + r) * DIM + off8) =
            pk4_i8(x2[v].x * rn2, x2[v].y * rn2, x2[v].z * rn2, x2[v].w * rn2);
    }
}

// ------- Kernel 2: i8 symmetric z.z^T; 512 full 256^2 tiles + 64 quarters ---
// Proven structure (sim 53.8us): BK=128, 8 barrier phases, A+B staged in LDS
// with the 3-bit involution bank swizzle; DPP rowsum reductions; 64 quarter
// jobs backfill the tail. All partials writes are STORES to disjoint slots
// (no accumulation) -> no memset needed; logred skips slot 32 for rows<4096.
__global__ __launch_bounds__(1024, 4) void sim_kernel(
    const unsigned char* __restrict__ zq,
    float* __restrict__ partials,    // [N2][PS]
    float* __restrict__ lup)         // [NT2*NT2], full-tile rt<=ct slots
{
    __shared__ __align__(16) unsigned char buf[2][2][BT * 128]; // 128 KB
    const int t    = threadIdx.x;
    const int lane = t & 63;
    const int wid  = t >> 6;       // 0..15
    const int fr   = lane & 15;    // fragment row (A) / col (B)
    const int kg   = lane >> 4;    // k-group 0..3
    const int cb0  = ((kg ^ (fr & 7)) << 4);                 // h=0 swizzled slot
    const int sgr8 = (((lane & 7) ^ ((lane >> 3) & 7)) << 4); // involution src
    const int rsub = (lane >> 4) << 2;
    const int csub = lane & 15;
    const int bid = blockIdx.x;

    if (bid < GRID_FULL) {
        // ---------------- full 256x256 tile ----------------
        int jj = (bid & 7) * 64 + (bid >> 3);   // bijective XCD swizzle
#pragma unroll 1
        for (int k = 16; k < 32; ++k) {         // skip quartered diag tiles
            const int e = k * 32 - ((k * (k - 1)) >> 1);
            if (jj >= e) ++jj;
        }
        int rt = 0;
        while ((rt + 1) * 32 - (((rt + 1) * rt) >> 1) <= jj) ++rt;
        const int ct = rt + jj - (rt * 32 - ((rt * (rt - 1)) >> 1));
        const bool isdiag = (rt == ct);
        const int row0 = rt << 8;
        const int col0 = ct << 8;
        const int wr = wid >> 2;    // 0..3 (64-row strip)
        const int wc = wid & 3;     // 0..3 (64-col strip)

        const int abase = ((wr << 6) + fr) << 7;   // row stride 128
        const int bbase = ((wc << 6) + fr) << 7;

        // staging: 64 chunks of 8 rows x 128B (A: 0-31, B: 32-63), 4/wave;
        // lane l: row l>>3, LDS slot l&7 (linear), global granule sgr8
        const int ar0 = row0 + ((wid << 1) << 3) + (lane >> 3);
        const int br0 = col0 + ((wid << 1) << 3) + (lane >> 3);
        const unsigned char* asrc = zq + (size_t)ar0 * DIM + sgr8;
        const unsigned char* bsrc = zq + (size_t)br0 * DIM + sgr8;

#define STAGEF(bsel, kp) do { \
        gload_lds16(asrc + (kp) * 128,              &buf[bsel][0][(wid << 11)]); \
        gload_lds16(asrc + (size_t)8 * DIM + (kp) * 128, &buf[bsel][0][(wid << 11) + 1024]); \
        gload_lds16(bsrc + (kp) * 128,              &buf[bsel][1][(wid << 11)]); \
        gload_lds16(bsrc + (size_t)8 * DIM + (kp) * 128, &buf[bsel][1][(wid << 11) + 1024]); \
    } while (0)

        i32x4 acc[4][4] = {};
        STAGEF(0, 0);
        __syncthreads();

#pragma unroll
        for (int kp = 0; kp < 8; ++kp) {
            const int cur = kp & 1;
            if (kp < 7) STAGEF(cur ^ 1, kp + 1);
            const unsigned char* Ab = &buf[cur][0][0] + abase;
            const unsigned char* Bb = &buf[cur][1][0] + bbase;
#pragma unroll
            for (int h = 0; h < 2; ++h) {
                const int cbh = cb0 ^ (h << 6);
                i32x4 bq[4];
#pragma unroll
                for (int n = 0; n < 4; ++n)
                    bq[n] = *(const i32x4*)(Bb + (n << 11) + cbh);
#pragma unroll
                for (int m = 0; m < 4; ++m) {
                    const i32x4 aq = *(const i32x4*)(Ab + (m << 11) + cbh);
#pragma unroll
                    for (int n = 0; n < 4; ++n)
                        acc[m][n] = __builtin_amdgcn_mfma_i32_16x16x64_i8(aq, bq[n], acc[m][n], 0, 0, 0);
                }
            }
            __syncthreads();
        }
#undef STAGEF

        // ---- epilogue: C/D layout col=lane&15, row=(lane>>4)*4+reg ----
        float* rsum4 = (float*)&buf[0][0][0];   // [256][4] per-(row,wc)
        float* csum4 = rsum4 + 1024;            // [256][4] per-(col,wr)
        float* lured = csum4 + 1024;            // [16]
        const bool inreg = (ct < 8) || (rt >= 8 && ct < 16);  // lunif blocks
        const int  rbase = row0 + (wr << 6);
        const int  cbase = col0 + (wc << 6);

        float lu = 0.0f;
        float cs[4] = {0.0f, 0.0f, 0.0f, 0.0f};
#pragma unroll
        for (int m = 0; m < 4; ++m) {
            float rs[4] = {0.0f, 0.0f, 0.0f, 0.0f};
#pragma unroll
            for (int n = 0; n < 4; ++n) {
                const int gcol = cbase + (n << 4) + csub;
#pragma unroll
                for (int r = 0; r < 4; ++r) {
                    const int grow = rbase + (m << 4) + rsub + r;
                    const float f = (float)acc[m][n][r];
                    float e = exp2f(f * C1f);
                    if (isdiag) e = (grow != gcol) ? e : 0.0f;
                    rs[r] += e;
                    cs[n] += e;
                    if (inreg && (!isdiag || gcol > grow))
                        lu += exp2f(fmaf(f, C2f, C2b));
                }
            }
#pragma unroll
            for (int r = 0; r < 4; ++r) rs[r] = rowsum16(rs[r]);   // DPP, VALU pipe
            if ((lane & 15) == 0) {
#pragma unroll
                for (int r = 0; r < 4; ++r)
                    rsum4[((wr << 6) + (m << 4) + rsub + r) * 4 + wc] = rs[r];
            }
        }
        if (!isdiag) {
#pragma unroll
            for (int off = 16; off < 64; off <<= 1) {
#pragma unroll
                for (int n = 0; n < 4; ++n) cs[n] += __shfl_xor(cs[n], off);
            }
            if (lane < 16) {
#pragma unroll
                for (int n = 0; n < 4; ++n)
                    csum4[((wc << 6) + (n << 4) + lane) * 4 + wr] = cs[n];
            }
        }
        lu = rowsum16(lu);
        lu += __shfl_xor(lu, 16);
        lu += __shfl_xor(lu, 32);
        if (lane == 0) lured[wid] = lu;
        __syncthreads();

        if (t == 0) {
            float s = 0.0f;
#pragma unroll
            for (int w = 0; w < 16; ++w) s += lured[w];
            lup[rt * NT2 + ct] = s;
        }
        if (t < 256) {
            const float* p = rsum4 + t * 4;
            partials[(size_t)(row0 + t) * PS + ct] = ((p[0] + p[1]) + p[2]) + p[3];
        } else if (t < 512 && !isdiag) {
            const float* p = csum4 + (t - 256) * 4;
            partials[(size_t)(col0 + t - 256) * PS + rt] = ((p[0] + p[1]) + p[2]) + p[3];
        }
    } else {
        // ------------- quarter 128x128 of diag tile (k,k), k=16..31 --------
        const int q  = bid - GRID_FULL;
        const int k  = 16 + (q >> 2);
        const int qr = (q >> 1) & 1;
        const int qc = q & 1;
        const int row0 = (k << 8) + (qr << 7);
        const int col0 = (k << 8) + (qc << 7);
        const int wr = wid >> 2;    // 0..3 (32-row strip)
        const int wc = wid & 3;     // 0..3 (32-col strip)

        // staging: 32 chunks of 8 rows (A: 0-15, B: 16-31), 2 per wave
        const int ch  = wid << 1;
        const int isB = ch >> 4;
        const int chl = ch & 15;
        const unsigned char* spanel =
            zq + (size_t)((isB ? col0 : row0) + (chl << 3) + (lane >> 3)) * DIM + sgr8;
        unsigned char* d0a = &buf[0][isB][chl << 10];
        unsigned char* d1a = &buf[1][isB][chl << 10];

        i32x4 acc[2][2] = {};
        gload_lds16(spanel, d0a);
        gload_lds16(spanel + (size_t)8 * DIM, d0a + 1024);
        __syncthreads();

#pragma unroll
        for (int kp = 0; kp < 8; ++kp) {
            const int cur = kp & 1;
            if (kp < 7) {
                unsigned char* dn = cur ? d0a : d1a;
                gload_lds16(spanel + (kp + 1) * 128, dn);
                gload_lds16(spanel + (size_t)8 * DIM + (kp + 1) * 128, dn + 1024);
            }
            const unsigned char* Ab = &buf[cur][0][0] + (((wr << 5) + fr) << 7);
            const unsigned char* Bb = &buf[cur][1][0] + (((wc << 5) + fr) << 7);
#pragma unroll
            for (int h = 0; h < 2; ++h) {
                const int cbh = cb0 ^ (h << 6);
                i32x4 aq[2], bq[2];
#pragma unroll
                for (int n = 0; n < 2; ++n)
                    bq[n] = *(const i32x4*)(Bb + (n << 11) + cbh);
#pragma unroll
                for (int m = 0; m < 2; ++m)
                    aq[m] = *(const i32x4*)(Ab + (m << 11) + cbh);
#pragma unroll
                for (int m = 0; m < 2; ++m)
#pragma unroll
                    for (int n = 0; n < 2; ++n)
                        acc[m][n] = __builtin_amdgcn_mfma_i32_16x16x64_i8(aq[m], bq[n], acc[m][n], 0, 0, 0);
            }
            __syncthreads();
        }

        // epilogue: rowsum only (z_j diag region: no colsum, no lunif)
        float* rsum4 = (float*)&buf[0][0][0];   // [128][4] per-(row,wc)
#pragma unroll
        for (int m = 0; m < 2; ++m) {
            float rs[4] = {0.0f, 0.0f, 0.0f, 0.0f};
#pragma unroll
            for (int n = 0; n < 2; ++n) {
                const int gcol = col0 + (wc << 5) + (n << 4) + csub;
#pragma unroll
                for (int r = 0; r < 4; ++r) {
                    const int grow = row0 + (wr << 5) + (m << 4) + rsub + r;
                    float e = exp2f((float)acc[m][n][r] * C1f);
                    e = (grow != gcol) ? e : 0.0f;   // diag mask (qr==qc quads)
                    rs[r] += e;
                }
            }
#pragma unroll
            for (int r = 0; r < 4; ++r) rs[r] = rowsum16(rs[r]);   // DPP
            if ((lane & 15) == 0) {
#pragma unroll
                for (int r = 0; r < 4; ++r)
                    rsum4[((wr << 5) + (m << 4) + rsub + r) * 4 + wc] = rs[r];
            }
        }
        __syncthreads();
        if (t < 128) {
            const float* p = rsum4 + t * 4;
            partials[(size_t)(row0 + t) * PS + (qc ? 32 : k)] =
                ((p[0] + p[1]) + p[2]) + p[3];
        }
    }
}

// --------- Kernel 3a: per-row denom -> log; also pre-reduce pos -------------
// Rows < NB (z_i half): aux slot 32 is never written -> sum 32 slots.
// Rows >= NB: quarters write slot 32 -> sum 33. (No memset needed: all
// partials writes are stores into exactly these slots.)
__global__ __launch_bounds__(128) void logred_kernel(
    const float* __restrict__ partials, const float* __restrict__ pos,
    double* __restrict__ red_log, double* __restrict__ red_pos)
{
    const int t   = threadIdx.x;
    const int row = blockIdx.x * 128 + t;
    const float* p = partials + (size_t)row * PS;
    float dsum = 0.0f;
#pragma unroll
    for (int i = 0; i < 32; ++i) dsum += p[i];
    if (row >= NB) dsum += p[32];
    double l = log((double)dsum);
    __shared__ double sd[128];
    sd[t] = l;
    __syncthreads();
    for (int s = 64; s > 0; s >>= 1) {
        if (t < s) sd[t] += sd[t + s];
        __syncthreads();
    }
    if (t == 0) red_log[blockIdx.x] = sd[0];
    __syncthreads();
    sd[t] = (t < 64) ? (double)pos[blockIdx.x * 64 + t] : 0.0;
    __syncthreads();
    for (int s = 32; s > 0; s >>= 1) {
        if (t < s) sd[t] += sd[t + s];
        __syncthreads();
    }
    if (t == 0) red_pos[blockIdx.x] = sd[0];
}

// --------- Kernel 3b: final scalars --------------------------------------
__global__ __launch_bounds__(256) void final_kernel(
    const double* __restrict__ red_log, const double* __restrict__ red_pos,
    const float* __restrict__ lup, float* __restrict__ out)
{
    const int t = threadIdx.x;
    double dlog = 0.0, dpos = 0.0, ds1 = 0.0, ds2 = 0.0;
    if (t < 64) { dlog = red_log[t]; dpos = red_pos[t]; }
    for (int i = t; i < NT2 * NT2; i += 256) {
        const int rt = i >> 5, ct = i & 31;
        if (rt > ct) continue;                 // only upper-tri tiles written
        const double v = (double)lup[i];
        if (rt < 8 && ct < 8) ds1 += v;
        else if (rt >= 8 && rt < 16 && ct >= 8 && ct < 16) ds2 += v;
    }
    __shared__ double sd[4][256];
    sd[0][t] = dlog; sd[1][t] = dpos; sd[2][t] = ds1; sd[3][t] = ds2;
    __syncthreads();
    for (int s = 128; s > 0; s >>= 1) {
        if (t < s) {
            sd[0][t] += sd[0][t + s]; sd[1][t] += sd[1][t + s];
            sd[2][t] += sd[2][t + s]; sd[3][t] += sd[3][t + s];
        }
        __syncthreads();
    }
    if (t == 0) {
        const double mean_pos = sd[1][0] / (double)NB;
        const double loss   = sd[0][0] / (double)N2 - mean_pos * 10.0;   // /TEMP
        const double lalign = 2.0 - 2.0 * mean_pos;
        const double C      = 2048.0 * 2047.0 * 0.5;
        const double lunif  = 0.5 * (log(sd[2][0] / C) + log(sd[3][0] / C));
        out[0] = (float)loss;
        out[1] = (float)lalign;
        out[2] = (float)lunif;
    }
}

extern "C" void kernel_launch(void* const* d_in, const int* in_sizes, int n_in,
                              void* d_out, int out_size, void* d_ws, size_t ws_size,
                              hipStream_t stream) {
    const float* p1 = (const float*)d_in[0];
    const float* p2 = (const float*)d_in[1];
    float* out = (float*)d_out;

    char* ws = (char*)d_ws;
    unsigned char* zq = (unsigned char*)ws;                              // 8 MB
    float*  partials  = (float*)(ws + ((size_t)8 << 20));                // ~1.1 MB [8192][34]
    float*  pos       = (float*)(ws + ((size_t)10 << 20));               // 16 KB
    float*  lup       = (float*)(ws + ((size_t)10 << 20) + 16384);       // 4 KB
    double* red_log   = (double*)(ws + ((size_t)10 << 20) + 16384 + 4096);  // 512 B
    double* red_pos   = (double*)(ws + ((size_t)10 << 20) + 16384 + 4096 + 512); // 512 B

    hipLaunchKernelGGL(norm_kernel,   dim3(NB / 4),   dim3(256),  0, stream, p1, p2, zq, pos);
    hipLaunchKernelGGL(sim_kernel,    dim3(GRID_ALL), dim3(1024), 0, stream, zq, partials, lup);
    hipLaunchKernelGGL(logred_kernel, dim3(64),       dim3(128),  0, stream, partials, pos, red_log, red_pos);
    hipLaunchKernelGGL(final_kernel,  dim3(1),        dim3(256),  0, stream, red_log, red_pos, lup, out);
}